// Round 1
// baseline (433.826 us; speedup 1.0000x reference)
//
#include <hip/hip_runtime.h>

// ResNeXt sparse-voxel block, MI355X. Round 0: correct f32 pipeline.
// Pipeline: lin GEMM -> gmap build -> gather-form sparse conv -> BN stats
//           (2-stage deterministic) -> fin GEMM (fused BN-norm+ReLU on A-load,
//           residual+bias epilogue).

#define NN    65536
#define CIN   128
#define CPATH 32
#define NPATH 4
#define NK    27

// ---------------------------------------------------------------------------
// Kernel 1: H = feats @ Wcat + bcat   (Wcat[k][p*32+c] = lin_W[p][k][c])
// 128x128 output tile per block, Ktile=32, 8x8 acc per thread.
// ---------------------------------------------------------------------------
__global__ void lin_gemm(const float* __restrict__ feats,
                         const float* __restrict__ linW,
                         const float* __restrict__ linb,
                         float* __restrict__ H) {
    __shared__ float As[32][132];   // As[k][row] (transposed for vector reads)
    __shared__ float Bs[32][132];
    const int tid = threadIdx.x;
    const int row0 = blockIdx.x * 128;
    const int rg = tid >> 4, cg = tid & 15;

    float acc[8][8];
#pragma unroll
    for (int i = 0; i < 8; i++)
#pragma unroll
        for (int j = 0; j < 8; j++) acc[i][j] = 0.f;

    for (int kt = 0; kt < 4; ++kt) {
        // A tile: feats[row0+r][kt*32 + kq*4 .. +3]
        {
            const int r = tid >> 3;
            const int kq = tid & 7;
#pragma unroll
            for (int i = 0; i < 4; i++) {
                const float4 v = *(const float4*)(feats +
                    (size_t)(row0 + r + 32 * i) * CIN + kt * 32 + kq * 4);
                As[kq * 4 + 0][r + 32 * i] = v.x;
                As[kq * 4 + 1][r + 32 * i] = v.y;
                As[kq * 4 + 2][r + 32 * i] = v.z;
                As[kq * 4 + 3][r + 32 * i] = v.w;
            }
        }
        // B tile: Bs[kk][col] = linW[(col>>5)][kt*32+kk][col&31]
        {
            const int col4 = (tid & 31) * 4;
            const int kk0 = tid >> 5;
            const int p = col4 >> 5;
#pragma unroll
            for (int i = 0; i < 4; i++) {
                const int kk = kk0 + 8 * i;
                const float4 w = *(const float4*)(linW +
                    ((size_t)(p * CIN) + (kt * 32 + kk)) * CPATH + (col4 & 31));
                *(float4*)&Bs[kk][col4] = w;
            }
        }
        __syncthreads();
#pragma unroll
        for (int kk = 0; kk < 32; kk++) {
            float a[8], b[8];
            *(float4*)&a[0] = *(const float4*)&As[kk][rg * 8];
            *(float4*)&a[4] = *(const float4*)&As[kk][rg * 8 + 4];
            *(float4*)&b[0] = *(const float4*)&Bs[kk][cg * 8];
            *(float4*)&b[4] = *(const float4*)&Bs[kk][cg * 8 + 4];
#pragma unroll
            for (int i = 0; i < 8; i++)
#pragma unroll
                for (int j = 0; j < 8; j++)
                    acc[i][j] = fmaf(a[i], b[j], acc[i][j]);
        }
        __syncthreads();
    }
    float bias[8];
#pragma unroll
    for (int j = 0; j < 8; j++) bias[j] = linb[cg * 8 + j];
#pragma unroll
    for (int i = 0; i < 8; i++) {
        const int row = row0 + rg * 8 + i;
        float4 o0, o1;
        o0.x = acc[i][0] + bias[0]; o0.y = acc[i][1] + bias[1];
        o0.z = acc[i][2] + bias[2]; o0.w = acc[i][3] + bias[3];
        o1.x = acc[i][4] + bias[4]; o1.y = acc[i][5] + bias[5];
        o1.z = acc[i][6] + bias[6]; o1.w = acc[i][7] + bias[7];
        *(float4*)(H + (size_t)row * CIN + cg * 8) = o0;
        *(float4*)(H + (size_t)row * CIN + cg * 8 + 4) = o1;
    }
}

// ---------------------------------------------------------------------------
// gmap: invert scatter maps into gather form. gmap[p][k][j] = in idx or NN.
// ---------------------------------------------------------------------------
__global__ void gmap_init(int* __restrict__ gmap) {
    const size_t total4 = (size_t)NPATH * NK * NN / 4;
    const size_t stride = (size_t)gridDim.x * blockDim.x;
    const int4 s = make_int4(NN, NN, NN, NN);
    for (size_t v = (size_t)blockIdx.x * blockDim.x + threadIdx.x;
         v < total4; v += stride)
        ((int4*)gmap)[v] = s;
}

__global__ void gmap_scatter(const int* __restrict__ om,
                             const int* __restrict__ im,
                             int* __restrict__ gmap) {
    const size_t total4 = (size_t)NPATH * NK * NN / 4;
    const size_t stride = (size_t)gridDim.x * blockDim.x;
    for (size_t v = (size_t)blockIdx.x * blockDim.x + threadIdx.x;
         v < total4; v += stride) {
        const int4 o4 = ((const int4*)om)[v];
        const int4 i4 = ((const int4*)im)[v];
        const size_t base = (v * 4) & ~(size_t)(NN - 1);  // (p,k) block base
        if (o4.x < NN) gmap[base + o4.x] = i4.x;
        if (o4.y < NN) gmap[base + o4.y] = i4.y;
        if (o4.z < NN) gmap[base + o4.z] = i4.z;
        if (o4.w < NN) gmap[base + o4.w] = i4.w;
    }
}

// ---------------------------------------------------------------------------
// Gather-form sparse conv: Cb[j][p*32+c] = sum_k H[gmap[p,k,j]][p*32+:] @ W[p,k]
// 32 lanes per output voxel (lane = out channel), 8 voxels per 256-thr block.
// ---------------------------------------------------------------------------
__global__ void sconv(const float* __restrict__ H,
                      const float* __restrict__ convW,
                      const int* __restrict__ gmap,
                      float* __restrict__ Cb) {
    const int p = blockIdx.y;
    const int lane = threadIdx.x & 31;   // output channel
    const int grp = threadIdx.x >> 5;    // voxel slot in block (0..7)
    const float* Wp = convW + (size_t)p * NK * CPATH * CPATH;
    const int* gm = gmap + (size_t)p * NK * NN;

    for (int jj = 0; jj < 8; ++jj) {
        const int j = blockIdx.x * 64 + jj * 8 + grp;
        float acc = 0.f;
        for (int k = 0; k < NK; ++k) {
            const int i = gm[(size_t)k * NN + j];
            if (i < NN) {
                const float* Hrow = H + (size_t)i * CIN + p * CPATH;
                float hr[32];
#pragma unroll
                for (int q = 0; q < 8; q++)
                    *(float4*)&hr[q * 4] = *(const float4*)(Hrow + q * 4);
                const float* Wk = Wp + (size_t)k * CPATH * CPATH;
#pragma unroll
                for (int m = 0; m < 32; m++)
                    acc = fmaf(hr[m], Wk[m * CPATH + lane], acc);
            }
        }
        Cb[(size_t)j * CIN + p * CPATH + lane] = acc;
    }
}

// ---------------------------------------------------------------------------
// BN stats, deterministic two-stage: per-block partial sum/sumsq, then reduce.
// ---------------------------------------------------------------------------
__global__ void bn_stats1(const float* __restrict__ Cb,
                          float* __restrict__ part) {
    const int c = threadIdx.x & 127;
    const int h = threadIdx.x >> 7;   // 0..1
    const int r0 = blockIdx.x * 256;
    float s = 0.f, s2 = 0.f;
    for (int r = h; r < 256; r += 2) {
        const float v = Cb[(size_t)(r0 + r) * CIN + c];
        s += v;
        s2 = fmaf(v, v, s2);
    }
    __shared__ float red[2][256];
    red[h][c] = s;
    red[h][128 + c] = s2;
    __syncthreads();
    if (h == 0) {
        part[(size_t)blockIdx.x * 256 + c] = s + red[1][c];
        part[(size_t)blockIdx.x * 256 + 128 + c] = s2 + red[1][128 + c];
    }
}

__global__ void bn_stats2(const float* __restrict__ part,
                          const float* __restrict__ gamma,
                          const float* __restrict__ beta,
                          float* __restrict__ ss) {
    const int c = threadIdx.x;  // 0..127 (= p*32 + cc)
    float s = 0.f, s2 = 0.f;
    for (int b = 0; b < 256; b++) {
        s += part[(size_t)b * 256 + c];
        s2 += part[(size_t)b * 256 + 128 + c];
    }
    const float mean = s * (1.f / NN);
    const float var = s2 * (1.f / NN) - mean * mean;
    const float sc = gamma[c] * rsqrtf(var + 1e-5f);
    ss[c] = sc;                       // scale
    ss[128 + c] = beta[c] - mean * sc; // shift
}

// ---------------------------------------------------------------------------
// Final GEMM: out = relu(norm(Cb)) @ finW + finb + feats
// Same tiling as lin_gemm; BN+ReLU applied while loading A tile.
// ---------------------------------------------------------------------------
__global__ void fin_gemm(const float* __restrict__ Cb,
                         const float* __restrict__ scale,
                         const float* __restrict__ shift,
                         const float* __restrict__ finW,
                         const float* __restrict__ finb,
                         const float* __restrict__ feats,
                         float* __restrict__ out) {
    __shared__ float As[32][132];
    __shared__ float Bs[32][132];
    const int tid = threadIdx.x;
    const int row0 = blockIdx.x * 128;
    const int rg = tid >> 4, cg = tid & 15;

    float acc[8][8];
#pragma unroll
    for (int i = 0; i < 8; i++)
#pragma unroll
        for (int j = 0; j < 8; j++) acc[i][j] = 0.f;

    for (int kt = 0; kt < 4; ++kt) {
        {
            const int r = tid >> 3;
            const int kq = tid & 7;
            const int kbase = kt * 32 + kq * 4;
            const float sc0 = scale[kbase + 0], sh0 = shift[kbase + 0];
            const float sc1 = scale[kbase + 1], sh1 = shift[kbase + 1];
            const float sc2 = scale[kbase + 2], sh2 = shift[kbase + 2];
            const float sc3 = scale[kbase + 3], sh3 = shift[kbase + 3];
#pragma unroll
            for (int i = 0; i < 4; i++) {
                const float4 v = *(const float4*)(Cb +
                    (size_t)(row0 + r + 32 * i) * CIN + kbase);
                As[kq * 4 + 0][r + 32 * i] = fmaxf(fmaf(v.x, sc0, sh0), 0.f);
                As[kq * 4 + 1][r + 32 * i] = fmaxf(fmaf(v.y, sc1, sh1), 0.f);
                As[kq * 4 + 2][r + 32 * i] = fmaxf(fmaf(v.z, sc2, sh2), 0.f);
                As[kq * 4 + 3][r + 32 * i] = fmaxf(fmaf(v.w, sc3, sh3), 0.f);
            }
        }
        {
            const int col4 = (tid & 31) * 4;
            const int kk0 = tid >> 5;
#pragma unroll
            for (int i = 0; i < 4; i++) {
                const int kk = kk0 + 8 * i;
                const float4 w = *(const float4*)(finW +
                    (size_t)(kt * 32 + kk) * CIN + col4);
                *(float4*)&Bs[kk][col4] = w;
            }
        }
        __syncthreads();
#pragma unroll
        for (int kk = 0; kk < 32; kk++) {
            float a[8], b[8];
            *(float4*)&a[0] = *(const float4*)&As[kk][rg * 8];
            *(float4*)&a[4] = *(const float4*)&As[kk][rg * 8 + 4];
            *(float4*)&b[0] = *(const float4*)&Bs[kk][cg * 8];
            *(float4*)&b[4] = *(const float4*)&Bs[kk][cg * 8 + 4];
#pragma unroll
            for (int i = 0; i < 8; i++)
#pragma unroll
                for (int j = 0; j < 8; j++)
                    acc[i][j] = fmaf(a[i], b[j], acc[i][j]);
        }
        __syncthreads();
    }
    float fb[8];
#pragma unroll
    for (int j = 0; j < 8; j++) fb[j] = finb[cg * 8 + j];
#pragma unroll
    for (int i = 0; i < 8; i++) {
        const int row = row0 + rg * 8 + i;
        const float4 r0 = *(const float4*)(feats + (size_t)row * CIN + cg * 8);
        const float4 r1 = *(const float4*)(feats + (size_t)row * CIN + cg * 8 + 4);
        float4 o0, o1;
        o0.x = acc[i][0] + fb[0] + r0.x; o0.y = acc[i][1] + fb[1] + r0.y;
        o0.z = acc[i][2] + fb[2] + r0.z; o0.w = acc[i][3] + fb[3] + r0.w;
        o1.x = acc[i][4] + fb[4] + r1.x; o1.y = acc[i][5] + fb[5] + r1.y;
        o1.z = acc[i][6] + fb[6] + r1.z; o1.w = acc[i][7] + fb[7] + r1.w;
        *(float4*)(out + (size_t)row * CIN + cg * 8) = o0;
        *(float4*)(out + (size_t)row * CIN + cg * 8 + 4) = o1;
    }
}

// ---------------------------------------------------------------------------
extern "C" void kernel_launch(void* const* d_in, const int* in_sizes, int n_in,
                              void* d_out, int out_size, void* d_ws,
                              size_t ws_size, hipStream_t stream) {
    (void)in_sizes; (void)n_in; (void)out_size; (void)ws_size;
    const float* feats = (const float*)d_in[0];
    const float* linW  = (const float*)d_in[1];
    const float* linb  = (const float*)d_in[2];
    const float* convW = (const float*)d_in[3];
    const float* gamma = (const float*)d_in[4];
    const float* beta  = (const float*)d_in[5];
    const float* finW  = (const float*)d_in[6];
    const float* finb  = (const float*)d_in[7];
    const int*   im    = (const int*)d_in[8];
    const int*   om    = (const int*)d_in[9];
    float* out = (float*)d_out;

    char* ws = (char*)d_ws;
    float* H    = (float*)(ws);                // 33,554,432 B
    float* Cb   = (float*)(ws + 33554432);     // 33,554,432 B
    int*   gmap = (int*)  (ws + 67108864);     // 28,311,552 B
    float* part = (float*)(ws + 95420416);     //    262,144 B
    float* ss   = (float*)(ws + 95682560);     //      1,024 B

    lin_gemm<<<512, 256, 0, stream>>>(feats, linW, linb, H);
    gmap_init<<<2048, 256, 0, stream>>>(gmap);
    gmap_scatter<<<2048, 256, 0, stream>>>(om, im, gmap);
    sconv<<<dim3(1024, 4), 256, 0, stream>>>(H, convW, gmap, Cb);
    bn_stats1<<<256, 256, 0, stream>>>(Cb, part);
    bn_stats2<<<1, 128, 0, stream>>>(part, gamma, beta, ss);
    fin_gemm<<<512, 256, 0, stream>>>(Cb, ss, ss + 128, finW, finb, feats, out);
}

// Round 2
// 213.972 us; speedup vs baseline: 2.0275x; 2.0275x over previous
//
#include <hip/hip_runtime.h>

// ResNeXt sparse-voxel block, MI355X. Round 1: pair-list sparse conv.
// sconv2 consumes the compact (in_map,out_map) pair lists directly per
// 256-voxel output tile (binary search on the sorted out_map prefix),
// accumulates deterministically into an LDS tile (k-offsets serialized by a
// barrier; within one k the output indices are unique -> race-free), and
// fuses the BN partial-sum reduction before writeback.

#define NN    65536
#define CIN   128
#define CPATH 32
#define NPATH 4
#define NK    27
#define TJ    256          // output voxels per tile
#define NTILE (NN / TJ)    // 256

// ---------------------------------------------------------------------------
// Kernel 1: H = feats @ Wcat + bcat   (Wcat[k][p*32+c] = lin_W[p][k][c])
// 128x128 output tile per block, Ktile=32, 8x8 acc per thread.
// ---------------------------------------------------------------------------
__global__ void lin_gemm(const float* __restrict__ feats,
                         const float* __restrict__ linW,
                         const float* __restrict__ linb,
                         float* __restrict__ H) {
    __shared__ float As[32][132];   // As[k][row] (transposed for vector reads)
    __shared__ float Bs[32][132];
    const int tid = threadIdx.x;
    const int row0 = blockIdx.x * 128;
    const int rg = tid >> 4, cg = tid & 15;

    float acc[8][8];
#pragma unroll
    for (int i = 0; i < 8; i++)
#pragma unroll
        for (int j = 0; j < 8; j++) acc[i][j] = 0.f;

    for (int kt = 0; kt < 4; ++kt) {
        {
            const int r = tid >> 3;
            const int kq = tid & 7;
#pragma unroll
            for (int i = 0; i < 4; i++) {
                const float4 v = *(const float4*)(feats +
                    (size_t)(row0 + r + 32 * i) * CIN + kt * 32 + kq * 4);
                As[kq * 4 + 0][r + 32 * i] = v.x;
                As[kq * 4 + 1][r + 32 * i] = v.y;
                As[kq * 4 + 2][r + 32 * i] = v.z;
                As[kq * 4 + 3][r + 32 * i] = v.w;
            }
        }
        {
            const int col4 = (tid & 31) * 4;
            const int kk0 = tid >> 5;
            const int p = col4 >> 5;
#pragma unroll
            for (int i = 0; i < 4; i++) {
                const int kk = kk0 + 8 * i;
                const float4 w = *(const float4*)(linW +
                    ((size_t)(p * CIN) + (kt * 32 + kk)) * CPATH + (col4 & 31));
                *(float4*)&Bs[kk][col4] = w;
            }
        }
        __syncthreads();
#pragma unroll
        for (int kk = 0; kk < 32; kk++) {
            float a[8], b[8];
            *(float4*)&a[0] = *(const float4*)&As[kk][rg * 8];
            *(float4*)&a[4] = *(const float4*)&As[kk][rg * 8 + 4];
            *(float4*)&b[0] = *(const float4*)&Bs[kk][cg * 8];
            *(float4*)&b[4] = *(const float4*)&Bs[kk][cg * 8 + 4];
#pragma unroll
            for (int i = 0; i < 8; i++)
#pragma unroll
                for (int j = 0; j < 8; j++)
                    acc[i][j] = fmaf(a[i], b[j], acc[i][j]);
        }
        __syncthreads();
    }
    float bias[8];
#pragma unroll
    for (int j = 0; j < 8; j++) bias[j] = linb[cg * 8 + j];
#pragma unroll
    for (int i = 0; i < 8; i++) {
        const int row = row0 + rg * 8 + i;
        float4 o0, o1;
        o0.x = acc[i][0] + bias[0]; o0.y = acc[i][1] + bias[1];
        o0.z = acc[i][2] + bias[2]; o0.w = acc[i][3] + bias[3];
        o1.x = acc[i][4] + bias[4]; o1.y = acc[i][5] + bias[5];
        o1.z = acc[i][6] + bias[6]; o1.w = acc[i][7] + bias[7];
        *(float4*)(H + (size_t)row * CIN + cg * 8) = o0;
        *(float4*)(H + (size_t)row * CIN + cg * 8 + 4) = o1;
    }
}

// ---------------------------------------------------------------------------
// sconv2: per (path, 256-voxel tile). Binary-search each of the 27 sorted
// out_map lists for this tile's range; process entries 32-at-a-time with
// 8 lanes per entry (4 out channels each); accumulate into LDS tile.
// Barrier between k's => deterministic accumulation order.
// Fused BN partial sums (per-block sum/sumsq per channel) before writeback.
// ---------------------------------------------------------------------------
__global__ void __launch_bounds__(256, 4)
sconv2(const float* __restrict__ H,
       const float* __restrict__ convW,
       const int* __restrict__ im,
       const int* __restrict__ om,
       float* __restrict__ Cb,
       float* __restrict__ part) {
    __shared__ float Ct[TJ][36];     // +4 pad: kills row-aliased bank conflicts
    __shared__ int rng[NK][2];
    __shared__ float red[8][64];

    const int p = blockIdx.y;
    const int j0 = blockIdx.x * TJ;
    const int tid = threadIdx.x;

    // zero the tile (9216 floats, 4 per thread per step, 9 steps exact)
    {
        float* ctf = &Ct[0][0];
        const float4 z = make_float4(0.f, 0.f, 0.f, 0.f);
#pragma unroll
        for (int idx = tid * 4; idx < TJ * 36; idx += 1024)
            *(float4*)&ctf[idx] = z;
    }
    // 54 parallel binary searches: [lo,hi) range of each k-list for this tile
    if (tid < NK * 2) {
        const int k = tid >> 1;
        const int bound = (tid & 1) ? (j0 + TJ) : j0;
        const int* o = om + ((size_t)p * NK + k) * NN;
        int lo = 0, hi = NN;
        while (lo < hi) {
            const int mid = (lo + hi) >> 1;
            if (o[mid] < bound) lo = mid + 1; else hi = mid;
        }
        rng[k][tid & 1] = lo;
    }
    __syncthreads();

    const int g = tid >> 3;        // entry slot (0..31)
    const int cq = tid & 7;        // channel quad (4 out channels)

    for (int k = 0; k < NK; ++k) {
        const int s = rng[k][0];
        const int e = rng[k][1];
        const int* ok = om + ((size_t)p * NK + k) * NN;
        const int* ik = im + ((size_t)p * NK + k) * NN;
        const float* Wk = convW + ((size_t)p * NK + k) * CPATH * CPATH;
        for (int t0 = s; t0 < e; t0 += 32) {
            const int t = t0 + g;
            if (t < e) {
                const int jj = ok[t] - j0;
                const int i = ik[t];
                const float4* Hr = (const float4*)(H + (size_t)i * CIN + p * CPATH);
                float4 h[8];
#pragma unroll
                for (int q = 0; q < 8; q++) h[q] = Hr[q];
                float4 a = make_float4(0.f, 0.f, 0.f, 0.f);
#pragma unroll
                for (int m = 0; m < 32; m++) {
                    const float hv = ((const float*)h)[m];
                    const float4 w = *(const float4*)(Wk + m * CPATH + cq * 4);
                    a.x = fmaf(hv, w.x, a.x);
                    a.y = fmaf(hv, w.y, a.y);
                    a.z = fmaf(hv, w.z, a.z);
                    a.w = fmaf(hv, w.w, a.w);
                }
                float4* ct = (float4*)&Ct[jj][cq * 4];
                float4 c0 = *ct;
                c0.x += a.x; c0.y += a.y; c0.z += a.z; c0.w += a.w;
                *ct = c0;
            }
        }
        __syncthreads();   // order k's: cross-k same-voxel collisions serialized
    }

    // fused BN partial sums over this tile: channel c = tid&31, slice h = tid>>5
    {
        const int c = tid & 31;
        const int h = tid >> 5;
        float s = 0.f, s2 = 0.f;
#pragma unroll
        for (int r = 0; r < 32; r++) {
            const float v = Ct[h * 32 + r][c];
            s += v;
            s2 = fmaf(v, v, s2);
        }
        red[h][c] = s;
        red[h][32 + c] = s2;
    }
    __syncthreads();
    if (tid < 64) {
        float s = red[0][tid];
#pragma unroll
        for (int h = 1; h < 8; h++) s += red[h][tid];
        part[(((size_t)p * NTILE) + blockIdx.x) * 64 + tid] = s;
    }

    // writeback: 8 rows x 32 ch per wave, coalesced 128B runs
    {
        const int r0 = tid >> 3;
#pragma unroll
        for (int m = 0; m < 8; m++) {
            const int r = r0 + 32 * m;
            *(float4*)(Cb + (size_t)(j0 + r) * CIN + p * CPATH + cq * 4) =
                *(const float4*)&Ct[r][cq * 4];
        }
    }
}

// ---------------------------------------------------------------------------
// BN finalize: reduce per-tile partials -> scale/shift per channel.
// ---------------------------------------------------------------------------
__global__ void bn_stats2(const float* __restrict__ part,
                          const float* __restrict__ gamma,
                          const float* __restrict__ beta,
                          float* __restrict__ ss) {
    const int c = threadIdx.x;  // 0..127 (= p*32 + cc)
    const int p = c >> 5, cc = c & 31;
    float s = 0.f, s2 = 0.f;
    for (int t = 0; t < NTILE; t++) {
        s += part[(((size_t)p * NTILE) + t) * 64 + cc];
        s2 += part[(((size_t)p * NTILE) + t) * 64 + 32 + cc];
    }
    const float mean = s * (1.f / NN);
    const float var = s2 * (1.f / NN) - mean * mean;
    const float sc = gamma[c] * rsqrtf(var + 1e-5f);
    ss[c] = sc;                        // scale
    ss[128 + c] = beta[c] - mean * sc; // shift
}

// ---------------------------------------------------------------------------
// Final GEMM: out = relu(norm(Cb)) @ finW + finb + feats
// ---------------------------------------------------------------------------
__global__ void fin_gemm(const float* __restrict__ Cb,
                         const float* __restrict__ scale,
                         const float* __restrict__ shift,
                         const float* __restrict__ finW,
                         const float* __restrict__ finb,
                         const float* __restrict__ feats,
                         float* __restrict__ out) {
    __shared__ float As[32][132];
    __shared__ float Bs[32][132];
    const int tid = threadIdx.x;
    const int row0 = blockIdx.x * 128;
    const int rg = tid >> 4, cg = tid & 15;

    float acc[8][8];
#pragma unroll
    for (int i = 0; i < 8; i++)
#pragma unroll
        for (int j = 0; j < 8; j++) acc[i][j] = 0.f;

    for (int kt = 0; kt < 4; ++kt) {
        {
            const int r = tid >> 3;
            const int kq = tid & 7;
            const int kbase = kt * 32 + kq * 4;
            const float sc0 = scale[kbase + 0], sh0 = shift[kbase + 0];
            const float sc1 = scale[kbase + 1], sh1 = shift[kbase + 1];
            const float sc2 = scale[kbase + 2], sh2 = shift[kbase + 2];
            const float sc3 = scale[kbase + 3], sh3 = shift[kbase + 3];
#pragma unroll
            for (int i = 0; i < 4; i++) {
                const float4 v = *(const float4*)(Cb +
                    (size_t)(row0 + r + 32 * i) * CIN + kbase);
                As[kq * 4 + 0][r + 32 * i] = fmaxf(fmaf(v.x, sc0, sh0), 0.f);
                As[kq * 4 + 1][r + 32 * i] = fmaxf(fmaf(v.y, sc1, sh1), 0.f);
                As[kq * 4 + 2][r + 32 * i] = fmaxf(fmaf(v.z, sc2, sh2), 0.f);
                As[kq * 4 + 3][r + 32 * i] = fmaxf(fmaf(v.w, sc3, sh3), 0.f);
            }
        }
        {
            const int col4 = (tid & 31) * 4;
            const int kk0 = tid >> 5;
#pragma unroll
            for (int i = 0; i < 4; i++) {
                const int kk = kk0 + 8 * i;
                const float4 w = *(const float4*)(finW +
                    (size_t)(kt * 32 + kk) * CIN + col4);
                *(float4*)&Bs[kk][col4] = w;
            }
        }
        __syncthreads();
#pragma unroll
        for (int kk = 0; kk < 32; kk++) {
            float a[8], b[8];
            *(float4*)&a[0] = *(const float4*)&As[kk][rg * 8];
            *(float4*)&a[4] = *(const float4*)&As[kk][rg * 8 + 4];
            *(float4*)&b[0] = *(const float4*)&Bs[kk][cg * 8];
            *(float4*)&b[4] = *(const float4*)&Bs[kk][cg * 8 + 4];
#pragma unroll
            for (int i = 0; i < 8; i++)
#pragma unroll
                for (int j = 0; j < 8; j++)
                    acc[i][j] = fmaf(a[i], b[j], acc[i][j]);
        }
        __syncthreads();
    }
    float fb[8];
#pragma unroll
    for (int j = 0; j < 8; j++) fb[j] = finb[cg * 8 + j];
#pragma unroll
    for (int i = 0; i < 8; i++) {
        const int row = row0 + rg * 8 + i;
        const float4 r0 = *(const float4*)(feats + (size_t)row * CIN + cg * 8);
        const float4 r1 = *(const float4*)(feats + (size_t)row * CIN + cg * 8 + 4);
        float4 o0, o1;
        o0.x = acc[i][0] + fb[0] + r0.x; o0.y = acc[i][1] + fb[1] + r0.y;
        o0.z = acc[i][2] + fb[2] + r0.z; o0.w = acc[i][3] + fb[3] + r0.w;
        o1.x = acc[i][4] + fb[4] + r1.x; o1.y = acc[i][5] + fb[5] + r1.y;
        o1.z = acc[i][6] + fb[6] + r1.z; o1.w = acc[i][7] + fb[7] + r1.w;
        *(float4*)(out + (size_t)row * CIN + cg * 8) = o0;
        *(float4*)(out + (size_t)row * CIN + cg * 8 + 4) = o1;
    }
}

// ---------------------------------------------------------------------------
extern "C" void kernel_launch(void* const* d_in, const int* in_sizes, int n_in,
                              void* d_out, int out_size, void* d_ws,
                              size_t ws_size, hipStream_t stream) {
    (void)in_sizes; (void)n_in; (void)out_size; (void)ws_size;
    const float* feats = (const float*)d_in[0];
    const float* linW  = (const float*)d_in[1];
    const float* linb  = (const float*)d_in[2];
    const float* convW = (const float*)d_in[3];
    const float* gamma = (const float*)d_in[4];
    const float* beta  = (const float*)d_in[5];
    const float* finW  = (const float*)d_in[6];
    const float* finb  = (const float*)d_in[7];
    const int*   im    = (const int*)d_in[8];
    const int*   om    = (const int*)d_in[9];
    float* out = (float*)d_out;

    char* ws = (char*)d_ws;
    float* H    = (float*)(ws);                // 33,554,432 B
    float* Cb   = (float*)(ws + 33554432);     // 33,554,432 B
    float* part = (float*)(ws + 67108864);     //    262,144 B
    float* ss   = (float*)(ws + 67371008);     //      1,024 B

    lin_gemm<<<512, 256, 0, stream>>>(feats, linW, linb, H);
    sconv2<<<dim3(NTILE, NPATH), 256, 0, stream>>>(H, convW, im, om, Cb, part);
    bn_stats2<<<1, 128, 0, stream>>>(part, gamma, beta, ss);
    fin_gemm<<<512, 256, 0, stream>>>(Cb, ss, ss + 128, finW, finb, feats, out);
}